// Round 1
// baseline (531.549 us; speedup 1.0000x reference)
//
#include <hip/hip_runtime.h>
#include <cstdint>

// ---------- types & helpers ----------
typedef unsigned short u16;
typedef __bf16 bf16x8 __attribute__((ext_vector_type(8)));
typedef float  f32x4  __attribute__((ext_vector_type(4)));

struct alignas(16) F4 { float v[4]; };
struct alignas(8)  U4 { u16 v[4]; };
struct alignas(16) U8 { u16 v[8]; };

__device__ __forceinline__ u16 f2bf(float f) {
    union { float f; unsigned int u; } x; x.f = f;
    unsigned int r = x.u + 0x7fffu + ((x.u >> 16) & 1u);   // RNE
    return (u16)(r >> 16);
}
__device__ __forceinline__ float bf2f(u16 u) {
    union { unsigned int u; float f; } x; x.u = ((unsigned int)u) << 16;
    return x.f;
}
__device__ __forceinline__ f32x4 mfma16(bf16x8 a, bf16x8 b, f32x4 c) {
    return __builtin_amdgcn_mfma_f32_16x16x32_bf16(a, b, c, 0, 0, 0);
}
// async global->LDS, 16B per lane, dest = wave-uniform base + lane*16 (CK-style casts)
__device__ __forceinline__ void gload_lds16(const void* g, void* l) {
    auto* gp = reinterpret_cast<const __attribute__((address_space(1))) unsigned int*>(
        reinterpret_cast<uintptr_t>(g));
    auto* lp = reinterpret_cast<__attribute__((address_space(3))) unsigned int*>(
        reinterpret_cast<uintptr_t>(l));
    __builtin_amdgcn_global_load_lds(gp, lp, 16, 0, 0);
}

// ---------- generic f32 -> bf16 cast (vector) ----------
__global__ __launch_bounds__(256) void cast_bf16_k(const float* __restrict__ in,
                                                   u16* __restrict__ out, int n4) {
    int i = blockIdx.x * 256 + threadIdx.x;
    if (i >= n4) return;
    F4 v = *(const F4*)(in + (size_t)i * 4);
    U4 o;
    #pragma unroll
    for (int j = 0; j < 4; ++j) o.v[j] = f2bf(v.v[j]);
    *(U4*)(out + (size_t)i * 4) = o;
}

// ---------- LayerNorm (C=1024), f32 in -> bf16 out ----------
__global__ __launch_bounds__(256) void ln_fwd_k(const float* __restrict__ x,
                                                const float* __restrict__ w,
                                                const float* __restrict__ b,
                                                u16* __restrict__ h) {
    const int row = blockIdx.x, tid = threadIdx.x;
    const float* xr = x + (size_t)row * 1024;
    F4 v = *(const F4*)(xr + tid * 4);
    float s  = v.v[0] + v.v[1] + v.v[2] + v.v[3];
    float ss = v.v[0]*v.v[0] + v.v[1]*v.v[1] + v.v[2]*v.v[2] + v.v[3]*v.v[3];
    #pragma unroll
    for (int o = 32; o > 0; o >>= 1) { s += __shfl_down(s, o); ss += __shfl_down(ss, o); }
    __shared__ float red[8];
    const int wave = tid >> 6, lane = tid & 63;
    if (lane == 0) { red[wave] = s; red[4 + wave] = ss; }
    __syncthreads();
    s  = red[0] + red[1] + red[2] + red[3];
    ss = red[4] + red[5] + red[6] + red[7];
    const float mu   = s * (1.0f / 1024.0f);
    const float var  = ss * (1.0f / 1024.0f) - mu * mu;
    const float rstd = rsqrtf(var + 1e-5f);
    U4 o;
    #pragma unroll
    for (int j = 0; j < 4; ++j)
        o.v[j] = f2bf((v.v[j] - mu) * rstd * w[tid * 4 + j] + b[tid * 4 + j]);
    *(U4*)(h + (size_t)row * 1024 + tid * 4) = o;
}

// ---------- GEMM: C[M,N] = A[M,K] * B[N,K]^T (both bf16 row-major, K-contiguous) ----------
// m97 structure: 128x128 tile, BK=32, 4 waves (2x2), 4x4 16x16 frags/wave, global_load_lds.
// MODE 0: store bf16 to Cout.  MODE 1: store f32 (resid[row,col] + acc) to Cout.
template <int MODE>
__global__ __launch_bounds__(256) void gemm_bt_k(const u16* __restrict__ A,
                                                 const u16* __restrict__ Bm,
                                                 void* __restrict__ Cout,
                                                 const float* __restrict__ resid,
                                                 int M, int N, int K) {
    __shared__ u16 Alds[128 * 32];
    __shared__ u16 Blds[128 * 32];
    const int tid  = threadIdx.x;
    const int lane = tid & 63, wave = tid >> 6;
    const int wr = wave >> 1, wc = wave & 1;
    const int r16 = lane & 15, g16 = lane >> 4;
    const int bn = blockIdx.x, bm = blockIdx.y;

    const int srow = lane >> 2;          // 0..15 within 16-row chunk
    const int scol = (lane & 3) * 8;     // 0,8,16,24

    f32x4 acc[4][4] = {};

    for (int k0 = 0; k0 < K; k0 += 32) {
        #pragma unroll
        for (int c = 0; c < 2; ++c) {
            const int ch = wave * 2 + c;                    // 0..7 (16 rows each)
            const u16* ga = A  + ((size_t)bm * 128 + ch * 16 + srow) * K + k0 + scol;
            gload_lds16(ga, &Alds[ch * 512]);
            const u16* gb = Bm + ((size_t)bn * 128 + ch * 16 + srow) * K + k0 + scol;
            gload_lds16(gb, &Blds[ch * 512]);
        }
        __syncthreads();
        bf16x8 af[4], bfr[4];
        #pragma unroll
        for (int m = 0; m < 4; ++m)
            af[m] = *(const bf16x8*)&Alds[(wr * 64 + m * 16 + r16) * 32 + g16 * 8];
        #pragma unroll
        for (int n = 0; n < 4; ++n)
            bfr[n] = *(const bf16x8*)&Blds[(wc * 64 + n * 16 + r16) * 32 + g16 * 8];
        #pragma unroll
        for (int m = 0; m < 4; ++m)
            #pragma unroll
            for (int n = 0; n < 4; ++n)
                acc[m][n] = mfma16(af[m], bfr[n], acc[m][n]);
        __syncthreads();
    }

    #pragma unroll
    for (int m = 0; m < 4; ++m) {
        #pragma unroll
        for (int n = 0; n < 4; ++n) {
            #pragma unroll
            for (int r = 0; r < 4; ++r) {
                const int row = bm * 128 + wr * 64 + m * 16 + g16 * 4 + r;
                const int col = bn * 128 + wc * 64 + n * 16 + r16;
                const float v = acc[m][n][r];
                if (MODE == 0) {
                    ((u16*)Cout)[(size_t)row * N + col] = f2bf(v);
                } else {
                    ((float*)Cout)[(size_t)row * N + col] =
                        resid[(size_t)row * N + col] + v;
                }
            }
        }
    }
}

// ---------- flash attention (causal), bf16 qkv in, bf16 O out ----------
// grid = B*H*(T/64); 4 waves, each owns 16 q-rows. KV step = 32.
__global__ __launch_bounds__(256) void attn_fwd_k(const u16* __restrict__ qkv,
                                                  u16* __restrict__ Ob) {
    __shared__ u16 Vt[64 * 32];        // V^T tile: [d (64)][kv (32)]
    __shared__ u16 Plds[4][16 * 32];   // per-wave P tile

    const int tid = threadIdx.x;
    const int wave = tid >> 6, lane = tid & 63;
    const int r16 = lane & 15, g16 = lane >> 4;

    const int bid = blockIdx.x;
    const int qb = bid & 31;            // T/64 = 32
    const int h  = (bid >> 5) & 15;
    const int b  = bid >> 9;

    const int q0w = qb * 64 + wave * 16;
    const size_t seqb = (size_t)b * 2048;

    bf16x8 qf0, qf1;
    {
        const u16* qp = qkv + (seqb + q0w + r16) * 3072 + h * 64 + g16 * 8;
        qf0 = *(const bf16x8*)qp;
        qf1 = *(const bf16x8*)(qp + 32);
    }

    f32x4 o[4] = {};
    float m[4], l[4];
    #pragma unroll
    for (int r = 0; r < 4; ++r) { m[r] = -3.0e38f; l[r] = 0.0f; }

    const int kv_end = qb * 64 + 64;
    for (int kv0 = 0; kv0 < kv_end; kv0 += 32) {
        { // stage V^T (all 256 threads)
            const int j  = tid >> 3;          // kv row 0..31
            const int d0 = (tid & 7) * 8;     // d 0..56
            const u16* vp = qkv + (seqb + kv0 + j) * 3072 + 2048 + h * 64 + d0;
            U8 vv = *(const U8*)vp;
            #pragma unroll
            for (int i = 0; i < 8; ++i) Vt[(d0 + i) * 32 + j] = vv.v[i];
        }
        __syncthreads();

        // scores: S[16q x 32kv] = Q . K^T (2 col-tiles, K-dim 64 = 2 MFMA each)
        f32x4 s0 = {0.f, 0.f, 0.f, 0.f}, s1 = {0.f, 0.f, 0.f, 0.f};
        {
            const u16* kp = qkv + (seqb + kv0 + r16) * 3072 + 1024 + h * 64 + g16 * 8;
            bf16x8 ka = *(const bf16x8*)kp;
            bf16x8 kb = *(const bf16x8*)(kp + 32);
            s0 = mfma16(qf0, ka, s0);
            s0 = mfma16(qf1, kb, s0);
            const u16* kp2 = kp + 16 * 3072;
            bf16x8 kc = *(const bf16x8*)kp2;
            bf16x8 kd = *(const bf16x8*)(kp2 + 32);
            s1 = mfma16(qf0, kc, s1);
            s1 = mfma16(qf1, kd, s1);
        }

        // online softmax; lane owns rows 4*g16+r, cols r16 / r16+16
        #pragma unroll
        for (int r = 0; r < 4; ++r) {
            const int qg = q0w + 4 * g16 + r;
            float a0 = (kv0 + r16      <= qg) ? s0[r] * 0.125f : -3.0e38f;
            float a1 = (kv0 + 16 + r16 <= qg) ? s1[r] * 0.125f : -3.0e38f;
            float mx = fmaxf(a0, a1);
            #pragma unroll
            for (int sft = 1; sft < 16; sft <<= 1) mx = fmaxf(mx, __shfl_xor(mx, sft));
            const float mn = fmaxf(m[r], mx);
            const float al = __expf(m[r] - mn);
            const float p0 = __expf(a0 - mn);
            const float p1 = __expf(a1 - mn);
            float rs = p0 + p1;
            #pragma unroll
            for (int sft = 1; sft < 16; sft <<= 1) rs += __shfl_xor(rs, sft);
            l[r] = l[r] * al + rs;
            m[r] = mn;
            Plds[wave][(4 * g16 + r) * 32 + r16]      = f2bf(p0);
            Plds[wave][(4 * g16 + r) * 32 + 16 + r16] = f2bf(p1);
            #pragma unroll
            for (int t = 0; t < 4; ++t) o[t][r] *= al;
        }
        __asm__ volatile("" ::: "memory");   // keep P writes before P reads (same wave, in-order LDS)

        // PV: o += P[16x32] . V[32x64]
        bf16x8 ap = *(const bf16x8*)&Plds[wave][r16 * 32 + g16 * 8];
        #pragma unroll
        for (int t = 0; t < 4; ++t) {
            bf16x8 vf = *(const bf16x8*)&Vt[(t * 16 + r16) * 32 + g16 * 8];
            o[t] = mfma16(ap, vf, o[t]);
        }
        __syncthreads();   // Vt consumed; safe to re-stage next iter
    }

    #pragma unroll
    for (int r = 0; r < 4; ++r) {
        const float inv = 1.0f / l[r];
        const int qg = q0w + 4 * g16 + r;
        u16* op = Ob + (seqb + qg) * 1024 + h * 64 + r16;
        #pragma unroll
        for (int t = 0; t < 4; ++t) op[t * 16] = f2bf(o[t][r] * inv);
    }
}

// ---------- SwiGLU elementwise: out = silu(a) * g (bf16) ----------
__global__ __launch_bounds__(256) void swiglu_k(const u16* __restrict__ a,
                                                const u16* __restrict__ g,
                                                u16* __restrict__ o, int n8) {
    int i = blockIdx.x * 256 + threadIdx.x;
    if (i >= n8) return;
    U8 av = *(const U8*)(a + (size_t)i * 8);
    U8 gv = *(const U8*)(g + (size_t)i * 8);
    U8 ov;
    #pragma unroll
    for (int j = 0; j < 8; ++j) {
        const float fa = bf2f(av.v[j]);
        const float fg = bf2f(gv.v[j]);
        const float s  = fa / (1.0f + __expf(-fa));
        ov.v[j] = f2bf(s * fg);
    }
    *(U8*)(o + (size_t)i * 8) = ov;
}

// ---------- launch ----------
extern "C" void kernel_launch(void* const* d_in, const int* in_sizes, int n_in,
                              void* d_out, int out_size, void* d_ws, size_t ws_size,
                              hipStream_t stream) {
    (void)in_sizes; (void)n_in; (void)out_size; (void)ws_size;
    constexpr int C = 1024, FF = 4096, M = 2 * 2048;   // B*T = 4096

    const float* x      = (const float*)d_in[0];
    const float* ln1_w  = (const float*)d_in[1];
    const float* ln1_b  = (const float*)d_in[2];
    const float* qkv_w  = (const float*)d_in[3];
    const float* atto_w = (const float*)d_in[4];
    const float* ln2_w  = (const float*)d_in[5];
    const float* ln2_b  = (const float*)d_in[6];
    const float* mlpi_w = (const float*)d_in[7];
    const float* mlpg_w = (const float*)d_in[8];
    const float* mlpo_w = (const float*)d_in[9];
    float* out = (float*)d_out;

    char* ws = (char*)d_ws;
    size_t off = 0;
    auto alloc = [&](size_t bytes) {
        char* p = ws + off;
        off += (bytes + 255) & ~(size_t)255;
        return p;
    };
    u16*   wq   = (u16*)  alloc((size_t)3 * C * C * 2);
    u16*   wo   = (u16*)  alloc((size_t)C * C * 2);
    u16*   wi   = (u16*)  alloc((size_t)FF * C * 2);
    u16*   wg   = (u16*)  alloc((size_t)FF * C * 2);
    u16*   wm   = (u16*)  alloc((size_t)C * FF * 2);
    u16*   h1   = (u16*)  alloc((size_t)M * C * 2);
    u16*   qkvb = (u16*)  alloc((size_t)M * 3 * C * 2);
    u16*   Ob   = (u16*)  alloc((size_t)M * C * 2);
    float* x1   = (float*)alloc((size_t)M * C * 4);
    u16*   h2   = (u16*)  alloc((size_t)M * C * 2);
    u16*   ab   = (u16*)  alloc((size_t)M * FF * 2);
    u16*   gb   = (u16*)  alloc((size_t)M * FF * 2);

    // weight casts (f32 -> bf16)
    cast_bf16_k<<<(3 * C * C / 4) / 256, 256, 0, stream>>>(qkv_w, wq, 3 * C * C / 4);
    cast_bf16_k<<<(C * C / 4) / 256, 256, 0, stream>>>(atto_w, wo, C * C / 4);
    cast_bf16_k<<<(FF * C / 4) / 256, 256, 0, stream>>>(mlpi_w, wi, FF * C / 4);
    cast_bf16_k<<<(FF * C / 4) / 256, 256, 0, stream>>>(mlpg_w, wg, FF * C / 4);
    cast_bf16_k<<<(C * FF / 4) / 256, 256, 0, stream>>>(mlpo_w, wm, C * FF / 4);

    // attention branch
    ln_fwd_k<<<M, 256, 0, stream>>>(x, ln1_w, ln1_b, h1);
    gemm_bt_k<0><<<dim3(3 * C / 128, M / 128), 256, 0, stream>>>(h1, wq, qkvb, nullptr, M, 3 * C, C);
    attn_fwd_k<<<2 * 16 * (2048 / 64), 256, 0, stream>>>(qkvb, Ob);
    gemm_bt_k<1><<<dim3(C / 128, M / 128), 256, 0, stream>>>(Ob, wo, x1, x, M, C, C);

    // MLP branch
    ln_fwd_k<<<M, 256, 0, stream>>>(x1, ln2_w, ln2_b, h2);
    gemm_bt_k<0><<<dim3(FF / 128, M / 128), 256, 0, stream>>>(h2, wi, ab, nullptr, M, FF, C);
    gemm_bt_k<0><<<dim3(FF / 128, M / 128), 256, 0, stream>>>(h2, wg, gb, nullptr, M, FF, C);
    swiglu_k<<<(M * FF / 8) / 256, 256, 0, stream>>>(ab, gb, ab, M * FF / 8);
    gemm_bt_k<1><<<dim3(C / 128, M / 128), 256, 0, stream>>>(ab, wm, out, x1, M, C, FF);
}